// Round 5
// baseline (617.022 us; speedup 1.0000x reference)
//
#include <hip/hip_runtime.h>
#include <stdint.h>

#define T_STEPS 100
#define BATCH   256
#define NIN     784
#define NHID    512
#define NOUT    10

// ===========================================================================
// NUMERICS CONTRACT (validated PASS R5/R6/R7/R12 — do not break):
//   * gemm1: per C element, fp32 single-accumulator fmaf chain, k ascending,
//     OpenBLAS kc=384 panel folds: cur1 = ((P1 + P2) + P3) + bias, each +
//     a single __fadd_rn. Realized here as:
//       gemm1_dual z=0: C1 = acc(k 0..383)      (pure write, mem1 region)
//       gemm1_dual z=1: C2 = acc(k 384..767)    (pure write, d_ws scratch)
//       leaky_hidden_fused: cur = fadd(fadd(fadd(C1,C2),acc3),b1), where
//         acc3 = 16-k ascending fmaf chain (k 768..783) computed in-register.
//     Op-for-op identical to the validated 3-launch P1/P2/tail version.
//   * gemm2: f64 accumulation of fp32 products, +b2 in f64, single rounding.
//   * recurrences: fp32 _rn ops, ((0.95*mem + cur) - rst), no contraction;
//     spike/reset = (mem > 1.0f).
// PERF JOURNAL:
//   * R5 570us: 8x8 single-buf, VALUBusy 36%, latency-bound (2 waves/SIMD).
//   * R6 2144us: __launch_bounds__(256,3) clamped VGPR->84, scratch spill,
//     9.5 GB HBM. Never use min-waves arg near the register boundary.
//   * R7 453us: dbuf 8x4, VGPR 148, VALUBusy 38% — LDS-pipe bound.
//   * R8 582us: 3-launch panel split -> 8x8 micro, BK=8, AGPR-clean acc
//     (VGPR 56!), panels 2x155us, VALUBusy 50%, HBM 10%.
//   * R9 645us REGRESSION: fusing tail into P2's epilogue broke the AGPR
//     allocation of acc[8][8] (VGPR 56->204, occ 22->9%, 155->249us).
//     LESSON: never touch acc non-trivially in the GEMM epilogue.
//   * R12 542.8us PASS: z=2 dual-panel launch (265.7us, VGPR 56, VALUBusy
//     62%, occ 31%, 0 conflicts), P2 scratch in d_ws (the spk1-aliasing
//     variant wedged containers twice — keep d_ws), tail+bias folded into
//     leaky_hidden. gemm1_dual = 49% of total; 48% of fp32 peak (floor
//     128us).
//   * R13: BK=8 -> BK=16. Barrier drains 48->24; compute window between
//     load-issue and vmcnt(0) 1024->2048cy, covering the ~900cy HBM-miss
//     latency of first-touch X loads. LDS 16.9->33.8KB (still 4 blocks/CU
//     = existing 4-wave/SIMD reg cap). Same k-ascending chain -> bit-exact.
// ===========================================================================

// ---------------------------------------------------------------------------
// GEMM1 dual-panel kernel: z=0 -> k 0..383 into C1; z=1 -> k 384..767 into
// C2. BM=BN=128, BK=16, 256 threads = 4 waves in 2x2; each wave 8x8 lanes;
// micro 8x8. Double-buffered LDS, one barrier per iteration, prefetch-ahead.
// Pure overwrite, epilogue untouched (keeps acc in AGPRs).
// ---------------------------------------------------------------------------
#define BM 128
#define BN 128
#define BK 16
#define PANEL_K 384

__global__ __launch_bounds__(256) void gemm1_dual(
    const float* __restrict__ X, const float* __restrict__ W,
    float* __restrict__ C1, float* __restrict__ C2)
{
    __shared__ float As[2][BK][BM + 4];   // 2 x 8448 B
    __shared__ float Bs[2][BK][BN + 4];   // 2 x 8448 B

    const int tid = threadIdx.x;
    const int bm  = blockIdx.x * BM;
    const int bn  = blockIdx.y * BN;
    const int kb  = blockIdx.z ? PANEL_K : 0;
    float* __restrict__ C = blockIdx.z ? C2 : C1;

    // staging: 128 rows x 16 k = 512 float4 per matrix; 2 float4/thread:
    // k segments [koff, koff+4) and [koff+8, koff+12)
    const int row  = tid >> 1;           // 0..127
    const int koff = (tid & 1) * 4;      // 0 or 4

    // compute mapping: wave 2x2, lane 8x8, micro 8x8
    const int w    = tid >> 6;
    const int lane = tid & 63;
    const int tm   = (w & 1) * 64 + (lane & 7) * 8;    // 0..120
    const int tn   = (w >> 1) * 64 + (lane >> 3) * 8;  // 0..120

    float acc[8][8];
    #pragma unroll
    for (int i = 0; i < 8; ++i)
        #pragma unroll
        for (int j = 0; j < 8; ++j) acc[i][j] = 0.f;

    const float* Xp = X + (size_t)(bm + row) * NIN + kb + koff;
    const float* Wp = W + (size_t)(bn + row) * NIN + kb + koff;

    // prologue: stage iter 0 into buffer 0
    float4 pa0 = *(const float4*)(Xp);
    float4 pa1 = *(const float4*)(Xp + 8);
    float4 pb0 = *(const float4*)(Wp);
    float4 pb1 = *(const float4*)(Wp + 8);
    As[0][koff+0][row] = pa0.x; As[0][koff+1][row] = pa0.y;
    As[0][koff+2][row] = pa0.z; As[0][koff+3][row] = pa0.w;
    As[0][koff+8][row] = pa1.x; As[0][koff+9][row] = pa1.y;
    As[0][koff+10][row] = pa1.z; As[0][koff+11][row] = pa1.w;
    Bs[0][koff+0][row] = pb0.x; Bs[0][koff+1][row] = pb0.y;
    Bs[0][koff+2][row] = pb0.z; Bs[0][koff+3][row] = pb0.w;
    Bs[0][koff+8][row] = pb1.x; Bs[0][koff+9][row] = pb1.y;
    Bs[0][koff+10][row] = pb1.z; Bs[0][koff+11][row] = pb1.w;

    const int NITER = PANEL_K / BK;   // 24
    for (int it = 0; it < NITER; ++it) {
        const int cur = it & 1;
        __syncthreads();

        if (it + 1 < NITER) {
            const int k0 = (it + 1) * BK;
            pa0 = *(const float4*)(Xp + k0);
            pa1 = *(const float4*)(Xp + k0 + 8);
            pb0 = *(const float4*)(Wp + k0);
            pb1 = *(const float4*)(Wp + k0 + 8);
        }

        #pragma unroll
        for (int kk = 0; kk < BK; ++kk) {   // k ascending
            float4 av0 = *(const float4*)&As[cur][kk][tm];
            float4 av1 = *(const float4*)&As[cur][kk][tm + 4];
            float4 bv0 = *(const float4*)&Bs[cur][kk][tn];
            float4 bv1 = *(const float4*)&Bs[cur][kk][tn + 4];
            float a[8] = {av0.x, av0.y, av0.z, av0.w, av1.x, av1.y, av1.z, av1.w};
            float b[8] = {bv0.x, bv0.y, bv0.z, bv0.w, bv1.x, bv1.y, bv1.z, bv1.w};
            #pragma unroll
            for (int i = 0; i < 8; ++i)
                #pragma unroll
                for (int j = 0; j < 8; ++j)
                    acc[i][j] = fmaf(a[i], b[j], acc[i][j]);
        }

        if (it + 1 < NITER) {
            const int nxt = cur ^ 1;
            As[nxt][koff+0][row] = pa0.x; As[nxt][koff+1][row] = pa0.y;
            As[nxt][koff+2][row] = pa0.z; As[nxt][koff+3][row] = pa0.w;
            As[nxt][koff+8][row] = pa1.x; As[nxt][koff+9][row] = pa1.y;
            As[nxt][koff+10][row] = pa1.z; As[nxt][koff+11][row] = pa1.w;
            Bs[nxt][koff+0][row] = pb0.x; Bs[nxt][koff+1][row] = pb0.y;
            Bs[nxt][koff+2][row] = pb0.z; Bs[nxt][koff+3][row] = pb0.w;
            Bs[nxt][koff+8][row] = pb1.x; Bs[nxt][koff+9][row] = pb1.y;
            Bs[nxt][koff+10][row] = pb1.z; Bs[nxt][koff+11][row] = pb1.w;
        }
    }

    #pragma unroll
    for (int i = 0; i < 8; ++i) {
        size_t r = (size_t)(bm + tm + i) * NHID + bn + tn;
        *(float4*)&C[r]     = make_float4(acc[i][0], acc[i][1], acc[i][2], acc[i][3]);
        *(float4*)&C[r + 4] = make_float4(acc[i][4], acc[i][5], acc[i][6], acc[i][7]);
    }
}

// ---------------------------------------------------------------------------
// Hidden Leaky recurrence, fused with the GEMM1 tail fold:
//   cur = fadd(fadd(fadd(P1, P2), acc3), b1)     [acc3 = 16-k fmaf chain]
//   mem = fsub(fadd(fmul(0.95, mem), cur), rst)
// One thread per (b,h) chain (131072). Depth-8 ring prefetch on BOTH partial
// streams. c2/spk_out NOT __restrict__: in the fallback path (tiny ws) they
// alias; ring reads [t+8] precede spike writes [t+8] in program order, same
// thread-column, so ordering is correct either way. W1 tail row lives in 16
// regs; X tail (64 B, uniform per block) is an L1 broadcast, prefetched one
// step ahead.
// ---------------------------------------------------------------------------
__global__ __launch_bounds__(256) void leaky_hidden_fused(
    float* __restrict__ mem_io,        // P1 on entry, mem1 on exit
    const float* c2,                   // P2 partial (may alias spk_out)
    float* spk_out,
    const float* __restrict__ X,
    const float* __restrict__ W1,
    const float* __restrict__ b1)
{
    const int idx = blockIdx.x * blockDim.x + threadIdx.x;  // 0..131071
    const size_t STRIDE = (size_t)BATCH * NHID;
    const int h  = idx & (NHID - 1);
    const int bb = idx >> 9;

    // W1[h][768..783] -> 16 regs
    const float* wp = W1 + (size_t)h * NIN + 768;
    float4 w0 = *(const float4*)(wp);
    float4 w1v = *(const float4*)(wp + 4);
    float4 w2v = *(const float4*)(wp + 8);
    float4 w3v = *(const float4*)(wp + 12);
    const float wt[16] = {w0.x, w0.y, w0.z, w0.w, w1v.x, w1v.y, w1v.z, w1v.w,
                          w2v.x, w2v.y, w2v.z, w2v.w, w3v.x, w3v.y, w3v.z, w3v.w};
    const float bias = b1[h];

    // X tail base for this thread's batch row; stride BATCH*NIN per t
    const size_t XT_STRIDE = (size_t)BATCH * NIN;
    const float* xb = X + (size_t)bb * NIN + 768;

    float buf1[8], buf2[8];
    #pragma unroll
    for (int i = 0; i < 8; ++i) {
        buf1[i] = mem_io[idx + (size_t)i * STRIDE];
        buf2[i] = c2[idx + (size_t)i * STRIDE];
    }

    // prefetch X tail for t=0
    float4 xa0 = *(const float4*)(xb);
    float4 xa1 = *(const float4*)(xb + 4);
    float4 xa2 = *(const float4*)(xb + 8);
    float4 xa3 = *(const float4*)(xb + 12);

    float mem = 0.f;
    for (int t = 0; t < T_STEPS; ++t) {
        const float p1 = buf1[t & 7];
        const float p2 = buf2[t & 7];
        const float xt[16] = {xa0.x, xa0.y, xa0.z, xa0.w, xa1.x, xa1.y, xa1.z, xa1.w,
                              xa2.x, xa2.y, xa2.z, xa2.w, xa3.x, xa3.y, xa3.z, xa3.w};

        const int tn = t + 8;
        if (tn < T_STEPS) {
            buf1[t & 7] = mem_io[idx + (size_t)tn * STRIDE];
            buf2[t & 7] = c2[idx + (size_t)tn * STRIDE];
        }
        if (t + 1 < T_STEPS) {
            const float* xn = xb + (size_t)(t + 1) * XT_STRIDE;
            xa0 = *(const float4*)(xn);
            xa1 = *(const float4*)(xn + 4);
            xa2 = *(const float4*)(xn + 8);
            xa3 = *(const float4*)(xn + 12);
        }

        // P3: 16-k ascending single-accumulator fmaf chain (bit-identical
        // to the old gemm1_tail acc chain).
        float acc3 = 0.f;
        #pragma unroll
        for (int kk = 0; kk < 16; ++kk)
            acc3 = fmaf(xt[kk], wt[kk], acc3);

        const float cur = __fadd_rn(__fadd_rn(__fadd_rn(p1, p2), acc3), bias);
        const float rst = (mem > 1.0f) ? 1.0f : 0.0f;
        mem = __fsub_rn(__fadd_rn(__fmul_rn(0.95f, mem), cur), rst);

        const size_t off = idx + (size_t)t * STRIDE;
        spk_out[off] = (mem > 1.0f) ? 1.0f : 0.0f;
        mem_io[off]  = mem;
    }
}

// ---------------------------------------------------------------------------
// GEMM2: cur2[m][o] = fl32( f64( sum_k spk1[m][k]*W2[o][k] + b2[o] ) )
// W2 (20 KB) staged in LDS. Block = 320 threads = 32 rows x 10 outputs.
// ---------------------------------------------------------------------------
#define G2_ROWS 32

__global__ __launch_bounds__(320) void gemm2_f64(
    const float* __restrict__ spk1, const float* __restrict__ W2,
    const float* __restrict__ b2, float* __restrict__ cur2)
{
    __shared__ float w2s[NOUT * NHID];  // 20 KB
    const int tid = threadIdx.x;
    for (int i = tid; i < NOUT * NHID; i += 320) w2s[i] = W2[i];
    __syncthreads();

    const int r = tid / NOUT;   // 0..31
    const int o = tid % NOUT;   // 0..9
    const size_t m = (size_t)blockIdx.x * G2_ROWS + r;
    const float* rowp = spk1 + m * NHID;
    const float* wp   = w2s + o * NHID;
    double dot = 0.0;
    #pragma unroll 4
    for (int k = 0; k < NHID; k += 4) {
        float4 s  = *(const float4*)(rowp + k);
        float4 wv = *(const float4*)(wp + k);
        dot = fma((double)s.x, (double)wv.x, dot);
        dot = fma((double)s.y, (double)wv.y, dot);
        dot = fma((double)s.z, (double)wv.z, dot);
        dot = fma((double)s.w, (double)wv.w, dot);
    }
    cur2[m * NOUT + o] = (float)(dot + (double)b2[o]);   // coalesced
}

// ---------------------------------------------------------------------------
// Output Leaky recurrence (fp32 _rn): one thread per (b,o) chain (2560).
// ---------------------------------------------------------------------------
__global__ __launch_bounds__(256) void leaky_out_kernel(
    const float* __restrict__ cur2, float* __restrict__ spk2,
    float* __restrict__ mem2)
{
    const int idx = blockIdx.x * blockDim.x + threadIdx.x;
    if (idx >= BATCH * NOUT) return;
    const int STRIDE = BATCH * NOUT;

    float buf[8];
    #pragma unroll
    for (int i = 0; i < 8; ++i) buf[i] = cur2[(size_t)i * STRIDE + idx];

    float mem = 0.f;
    #pragma unroll 4
    for (int t = 0; t < T_STEPS; ++t) {
        float cur = buf[t & 7];
        int tn = t + 8;
        if (tn < T_STEPS) buf[t & 7] = cur2[(size_t)tn * STRIDE + idx];
        float rst = (mem > 1.0f) ? 1.0f : 0.0f;
        mem = __fsub_rn(__fadd_rn(__fmul_rn(0.95f, mem), cur), rst);
        size_t off = (size_t)t * STRIDE + idx;
        spk2[off] = (mem > 1.0f) ? 1.0f : 0.0f;
        mem2[off] = mem;
    }
}

// ---------------------------------------------------------------------------
extern "C" void kernel_launch(void* const* d_in, const int* in_sizes, int n_in,
                              void* d_out, int out_size, void* d_ws, size_t ws_size,
                              hipStream_t stream) {
    const float* x  = (const float*)d_in[0];   // (100, 256, 784)
    const float* w1 = (const float*)d_in[1];   // (512, 784)
    const float* b1 = (const float*)d_in[2];   // (512,)
    const float* w2 = (const float*)d_in[3];   // (10, 512)
    const float* b2 = (const float*)d_in[4];   // (10,)

    float* out = (float*)d_out;
    // Output tuple order: (cur2, spk2, spk1, mem2, mem1), each stacked over T.
    float* cur2_out = out;                       // 256000
    float* spk2_out = out + 256000;              // 256000
    float* spk1_out = out + 512000;              // 13107200
    float* mem2_out = out + 13619200;            // 256000
    float* mem1_out = out + 13875200;            // 13107200

    const int M = T_STEPS * BATCH;               // 25600

    // P2 scratch: prefer d_ws (no aliasing); fall back to spk1 region
    // (per-thread-column safe aliasing) only if workspace is too small.
    const size_t p2_bytes = (size_t)M * NHID * sizeof(float);   // 52.4 MB
    float* p2buf = (d_ws != nullptr && ws_size >= p2_bytes)
                       ? (float*)d_ws : spk1_out;

    // 1) P1 -> mem1 region, P2 -> p2buf, one z=2 launch.
    dim3 gp(M / BM, NHID / BN, 2);               // (200, 4, 2) = 1600 blocks
    gemm1_dual<<<gp, 256, 0, stream>>>(x, w1, mem1_out, p2buf);

    // 2) hidden Leaky chains + P3 tail fold + bias (fp32 _rn):
    //    reads P1 (mem1 region) + P2 (p2buf), writes mem1 + spk1.
    leaky_hidden_fused<<<(BATCH * NHID) / 256, 256, 0, stream>>>(
        mem1_out, p2buf, spk1_out, x, w1, b1);

    // 3) cur2 = spk1 @ W2^T + b2 (f64 acc -> fp32)
    gemm2_f64<<<M / G2_ROWS, 320, 0, stream>>>(spk1_out, w2, b2, cur2_out);

    // 4) output Leaky chains (fp32 _rn): cur2 -> (spk2, mem2)
    leaky_out_kernel<<<(BATCH * NOUT + 255) / 256, 256, 0, stream>>>(
        cur2_out, spk2_out, mem2_out);
}

// Round 6
// 495.151 us; speedup vs baseline: 1.2461x; 1.2461x over previous
//
#include <hip/hip_runtime.h>
#include <stdint.h>

#define T_STEPS 100
#define BATCH   256
#define NIN     784
#define NHID    512
#define NOUT    10

// ===========================================================================
// NUMERICS CONTRACT (validated PASS R5/R6/R7/R12 — do not break):
//   * gemm1: per C element, fp32 single-accumulator fmaf chain, k ascending,
//     OpenBLAS kc=384 panel folds: cur1 = ((P1 + P2) + P3) + bias, each +
//     a single __fadd_rn. Realized here as:
//       gemm1_dual z=0: C1 = acc(k 0..383)      (pure write, mem1 region)
//       gemm1_dual z=1: C2 = acc(k 384..767)    (pure write, d_ws scratch)
//       leaky_hidden_fused: cur = fadd(fadd(fadd(C1,C2),acc3),b1), where
//         acc3 = 16-k ascending fmaf chain (k 768..783) computed in-register.
//     Op-for-op identical to the validated 3-launch P1/P2/tail version.
//   * gemm2: f64 accumulation of fp32 products, +b2 in f64, single rounding.
//   * recurrences: fp32 _rn ops, ((0.95*mem + cur) - rst), no contraction;
//     spike/reset = (mem > 1.0f).
// PERF JOURNAL:
//   * R5 570us: 8x8 single-buf, VALUBusy 36%, latency-bound (2 waves/SIMD).
//   * R6 2144us: __launch_bounds__(256,3) clamped VGPR->84, scratch spill.
//     Never use min-waves arg near the register boundary.
//   * R7 453us: dbuf 8x4, VGPR 148, VALUBusy 38% — LDS-pipe bound.
//   * R8 582us: 3-launch panel split -> 8x8 micro, BK=8, AGPR-clean acc
//     (VGPR 56!), panels 2x155us, VALUBusy 50%, HBM 10%.
//   * R9 645us REGRESSION: fusing tail into P2's epilogue broke the AGPR
//     allocation of acc[8][8] (VGPR 56->204, occ 22->9%).
//     LESSON: never touch acc non-trivially in the GEMM epilogue.
//   * R12 542.8us PASS: z=2 dual-panel launch (265.7us, VGPR 56, VALUBusy
//     62%, occ 31%, 0 conflicts), P2 scratch in d_ws, tail+bias folded into
//     leaky_hidden. gemm1_dual = 49% of total; 48% of fp32 peak.
//   * R13 617us REGRESSION: BK=16 doubled staging regs -> VGPR 56->176,
//     occ 10.4%, gemm1 386us. LESSON: BK=8 + one-float4-per-matrix staging
//     is exactly what keeps acc in AGPRs. Do not widen staging.
//   * R14: gemm1_dual reverted to R12 bytes. leaky_hidden_fused v2:
//     X-tail staged once in LDS (6.4KB, broadcast reads), acc3 computed
//     one step ahead (off the recurrence critical path), t-loop unrolled
//     x8 so ring indices are static (no scratch risk).
// ===========================================================================

// ---------------------------------------------------------------------------
// GEMM1 dual-panel kernel: z=0 -> k 0..383 into C1; z=1 -> k 384..767 into
// C2. BM=BN=128, BK=8, 256 threads = 4 waves in 2x2; each wave 8x8 lanes;
// micro 8x8. Double-buffered LDS, one barrier per iteration, prefetch-ahead.
// Pure overwrite, epilogue untouched (keeps acc in AGPRs, VGPR ~56).
// ---------------------------------------------------------------------------
#define BM 128
#define BN 128
#define BK 8
#define PANEL_K 384

__global__ __launch_bounds__(256) void gemm1_dual(
    const float* __restrict__ X, const float* __restrict__ W,
    float* __restrict__ C1, float* __restrict__ C2)
{
    __shared__ float As[2][BK][BM + 4];   // 2 x 4224 B
    __shared__ float Bs[2][BK][BN + 4];   // 2 x 4224 B

    const int tid = threadIdx.x;
    const int bm  = blockIdx.x * BM;
    const int bn  = blockIdx.y * BN;
    const int kb  = blockIdx.z ? PANEL_K : 0;
    float* __restrict__ C = blockIdx.z ? C2 : C1;

    // staging: 128 rows x 8 k = 256 float4
    const int row  = tid >> 1;           // 0..127
    const int koff = (tid & 1) * 4;      // 0 or 4

    // compute mapping: wave 2x2, lane 8x8, micro 8x8
    const int w    = tid >> 6;
    const int lane = tid & 63;
    const int tm   = (w & 1) * 64 + (lane & 7) * 8;    // 0..120
    const int tn   = (w >> 1) * 64 + (lane >> 3) * 8;  // 0..120

    float acc[8][8];
    #pragma unroll
    for (int i = 0; i < 8; ++i)
        #pragma unroll
        for (int j = 0; j < 8; ++j) acc[i][j] = 0.f;

    const float* Xp = X + (size_t)(bm + row) * NIN + kb + koff;
    const float* Wp = W + (size_t)(bn + row) * NIN + kb + koff;

    // prologue: stage iter 0 into buffer 0
    float4 pa = *(const float4*)(Xp);
    float4 pb = *(const float4*)(Wp);
    As[0][koff+0][row] = pa.x; As[0][koff+1][row] = pa.y;
    As[0][koff+2][row] = pa.z; As[0][koff+3][row] = pa.w;
    Bs[0][koff+0][row] = pb.x; Bs[0][koff+1][row] = pb.y;
    Bs[0][koff+2][row] = pb.z; Bs[0][koff+3][row] = pb.w;

    const int NITER = PANEL_K / BK;   // 48
    for (int it = 0; it < NITER; ++it) {
        const int cur = it & 1;
        __syncthreads();

        if (it + 1 < NITER) {
            const int k0 = (it + 1) * BK;
            pa = *(const float4*)(Xp + k0);
            pb = *(const float4*)(Wp + k0);
        }

        #pragma unroll
        for (int kk = 0; kk < BK; ++kk) {   // k ascending
            float4 av0 = *(const float4*)&As[cur][kk][tm];
            float4 av1 = *(const float4*)&As[cur][kk][tm + 4];
            float4 bv0 = *(const float4*)&Bs[cur][kk][tn];
            float4 bv1 = *(const float4*)&Bs[cur][kk][tn + 4];
            float a[8] = {av0.x, av0.y, av0.z, av0.w, av1.x, av1.y, av1.z, av1.w};
            float b[8] = {bv0.x, bv0.y, bv0.z, bv0.w, bv1.x, bv1.y, bv1.z, bv1.w};
            #pragma unroll
            for (int i = 0; i < 8; ++i)
                #pragma unroll
                for (int j = 0; j < 8; ++j)
                    acc[i][j] = fmaf(a[i], b[j], acc[i][j]);
        }

        if (it + 1 < NITER) {
            const int nxt = cur ^ 1;
            As[nxt][koff+0][row] = pa.x; As[nxt][koff+1][row] = pa.y;
            As[nxt][koff+2][row] = pa.z; As[nxt][koff+3][row] = pa.w;
            Bs[nxt][koff+0][row] = pb.x; Bs[nxt][koff+1][row] = pb.y;
            Bs[nxt][koff+2][row] = pb.z; Bs[nxt][koff+3][row] = pb.w;
        }
    }

    #pragma unroll
    for (int i = 0; i < 8; ++i) {
        size_t r = (size_t)(bm + tm + i) * NHID + bn + tn;
        *(float4*)&C[r]     = make_float4(acc[i][0], acc[i][1], acc[i][2], acc[i][3]);
        *(float4*)&C[r + 4] = make_float4(acc[i][4], acc[i][5], acc[i][6], acc[i][7]);
    }
}

// ---------------------------------------------------------------------------
// Hidden Leaky recurrence, fused with the GEMM1 tail fold (v2):
//   cur = fadd(fadd(fadd(P1, P2), acc3), b1)     [acc3 = 16-k fmaf chain]
//   mem = fsub(fadd(fmul(0.95, mem), cur), rst)
// One thread per (b,h) chain (131072). Block = 256 threads = one batch row
// half; the block's X-tail (100 t x 16 k = 6.4 KB) is staged ONCE in LDS and
// read per-iteration via 4 broadcast ds_read_b128 (conflict-free). acc3 for
// t+1 is computed during iteration t (off the recurrence critical path).
// t-loop unrolled in static blocks of 8 so ring indices are compile-time.
// Identical k-ascending fmaf chain on identical values -> bit-exact.
// ---------------------------------------------------------------------------
__global__ __launch_bounds__(256) void leaky_hidden_fused(
    float* __restrict__ mem_io,        // P1 on entry, mem1 on exit
    const float* __restrict__ c2,      // P2 partial (d_ws)
    float* __restrict__ spk_out,
    const float* __restrict__ X,
    const float* __restrict__ W1,
    const float* __restrict__ b1)
{
    __shared__ float4 xs4[T_STEPS][4];   // X[bb][t][768..783], 6.4 KB

    const int tid = threadIdx.x;
    const int idx = blockIdx.x * 256 + tid;    // 0..131071
    const size_t STRIDE = (size_t)BATCH * NHID;
    const int h  = idx & (NHID - 1);
    const int bb = idx >> 9;                   // uniform per block

    // stage X tail: 400 float4 across 256 threads
    {
        const float* xbase = X + (size_t)bb * NIN + 768;
        for (int e = tid; e < T_STEPS * 4; e += 256) {
            const int t = e >> 2, q = e & 3;
            xs4[t][q] = *(const float4*)(xbase + (size_t)t * BATCH * NIN + q * 4);
        }
    }

    // W1[h][768..783] -> 16 regs
    const float* wp = W1 + (size_t)h * NIN + 768;
    float4 w0 = *(const float4*)(wp);
    float4 w1v = *(const float4*)(wp + 4);
    float4 w2v = *(const float4*)(wp + 8);
    float4 w3v = *(const float4*)(wp + 12);
    const float wt[16] = {w0.x, w0.y, w0.z, w0.w, w1v.x, w1v.y, w1v.z, w1v.w,
                          w2v.x, w2v.y, w2v.z, w2v.w, w3v.x, w3v.y, w3v.z, w3v.w};
    const float bias = b1[h];

    float buf1[8], buf2[8];
    #pragma unroll
    for (int i = 0; i < 8; ++i) {
        buf1[i] = mem_io[idx + (size_t)i * STRIDE];
        buf2[i] = c2[idx + (size_t)i * STRIDE];
    }

    __syncthreads();   // xs4 ready

    // acc3 for t=0 (identical k-ascending chain, LDS-sourced)
    float a3cur;
    {
        float4 v0 = xs4[0][0], v1 = xs4[0][1], v2 = xs4[0][2], v3 = xs4[0][3];
        float a = 0.f;
        a = fmaf(v0.x, wt[0], a);  a = fmaf(v0.y, wt[1], a);
        a = fmaf(v0.z, wt[2], a);  a = fmaf(v0.w, wt[3], a);
        a = fmaf(v1.x, wt[4], a);  a = fmaf(v1.y, wt[5], a);
        a = fmaf(v1.z, wt[6], a);  a = fmaf(v1.w, wt[7], a);
        a = fmaf(v2.x, wt[8], a);  a = fmaf(v2.y, wt[9], a);
        a = fmaf(v2.z, wt[10], a); a = fmaf(v2.w, wt[11], a);
        a = fmaf(v3.x, wt[12], a); a = fmaf(v3.y, wt[13], a);
        a = fmaf(v3.z, wt[14], a); a = fmaf(v3.w, wt[15], a);
        a3cur = a;
    }

    float mem = 0.f;

    #define LH_BODY(T_, J_)                                                   \
    {                                                                         \
        const int t_ = (T_);                                                  \
        const float p1 = buf1[(J_)];                                          \
        const float p2 = buf2[(J_)];                                          \
        if (t_ + 8 < T_STEPS) {                                               \
            buf1[(J_)] = mem_io[idx + (size_t)(t_ + 8) * STRIDE];             \
            buf2[(J_)] = c2[idx + (size_t)(t_ + 8) * STRIDE];                 \
        }                                                                     \
        float a3next = 0.f;                                                   \
        if (t_ + 1 < T_STEPS) {                                               \
            float4 v0 = xs4[t_ + 1][0], v1 = xs4[t_ + 1][1];                  \
            float4 v2 = xs4[t_ + 1][2], v3 = xs4[t_ + 1][3];                  \
            float a = 0.f;                                                    \
            a = fmaf(v0.x, wt[0], a);  a = fmaf(v0.y, wt[1], a);              \
            a = fmaf(v0.z, wt[2], a);  a = fmaf(v0.w, wt[3], a);              \
            a = fmaf(v1.x, wt[4], a);  a = fmaf(v1.y, wt[5], a);              \
            a = fmaf(v1.z, wt[6], a);  a = fmaf(v1.w, wt[7], a);              \
            a = fmaf(v2.x, wt[8], a);  a = fmaf(v2.y, wt[9], a);              \
            a = fmaf(v2.z, wt[10], a); a = fmaf(v2.w, wt[11], a);             \
            a = fmaf(v3.x, wt[12], a); a = fmaf(v3.y, wt[13], a);             \
            a = fmaf(v3.z, wt[14], a); a = fmaf(v3.w, wt[15], a);             \
            a3next = a;                                                       \
        }                                                                     \
        const float cur = __fadd_rn(__fadd_rn(__fadd_rn(p1, p2), a3cur), bias); \
        const float rst = (mem > 1.0f) ? 1.0f : 0.0f;                         \
        mem = __fsub_rn(__fadd_rn(__fmul_rn(0.95f, mem), cur), rst);          \
        const size_t off = idx + (size_t)t_ * STRIDE;                         \
        spk_out[off] = (mem > 1.0f) ? 1.0f : 0.0f;                            \
        mem_io[off]  = mem;                                                   \
        a3cur = a3next;                                                       \
    }

    for (int tb = 0; tb < 96; tb += 8) {
        LH_BODY(tb + 0, 0) LH_BODY(tb + 1, 1) LH_BODY(tb + 2, 2) LH_BODY(tb + 3, 3)
        LH_BODY(tb + 4, 4) LH_BODY(tb + 5, 5) LH_BODY(tb + 6, 6) LH_BODY(tb + 7, 7)
    }
    // tail t = 96..99 (ring slots 0..3, no prefetch fires: t+8 >= 104)
    LH_BODY(96, 0) LH_BODY(97, 1) LH_BODY(98, 2) LH_BODY(99, 3)

    #undef LH_BODY
}

// ---------------------------------------------------------------------------
// GEMM2: cur2[m][o] = fl32( f64( sum_k spk1[m][k]*W2[o][k] + b2[o] ) )
// W2 (20 KB) staged in LDS. Block = 320 threads = 32 rows x 10 outputs.
// ---------------------------------------------------------------------------
#define G2_ROWS 32

__global__ __launch_bounds__(320) void gemm2_f64(
    const float* __restrict__ spk1, const float* __restrict__ W2,
    const float* __restrict__ b2, float* __restrict__ cur2)
{
    __shared__ float w2s[NOUT * NHID];  // 20 KB
    const int tid = threadIdx.x;
    for (int i = tid; i < NOUT * NHID; i += 320) w2s[i] = W2[i];
    __syncthreads();

    const int r = tid / NOUT;   // 0..31
    const int o = tid % NOUT;   // 0..9
    const size_t m = (size_t)blockIdx.x * G2_ROWS + r;
    const float* rowp = spk1 + m * NHID;
    const float* wp   = w2s + o * NHID;
    double dot = 0.0;
    #pragma unroll 4
    for (int k = 0; k < NHID; k += 4) {
        float4 s  = *(const float4*)(rowp + k);
        float4 wv = *(const float4*)(wp + k);
        dot = fma((double)s.x, (double)wv.x, dot);
        dot = fma((double)s.y, (double)wv.y, dot);
        dot = fma((double)s.z, (double)wv.z, dot);
        dot = fma((double)s.w, (double)wv.w, dot);
    }
    cur2[m * NOUT + o] = (float)(dot + (double)b2[o]);   // coalesced
}

// ---------------------------------------------------------------------------
// Output Leaky recurrence (fp32 _rn): one thread per (b,o) chain (2560).
// ---------------------------------------------------------------------------
__global__ __launch_bounds__(256) void leaky_out_kernel(
    const float* __restrict__ cur2, float* __restrict__ spk2,
    float* __restrict__ mem2)
{
    const int idx = blockIdx.x * blockDim.x + threadIdx.x;
    if (idx >= BATCH * NOUT) return;
    const int STRIDE = BATCH * NOUT;

    float buf[8];
    #pragma unroll
    for (int i = 0; i < 8; ++i) buf[i] = cur2[(size_t)i * STRIDE + idx];

    float mem = 0.f;
    #pragma unroll 4
    for (int t = 0; t < T_STEPS; ++t) {
        float cur = buf[t & 7];
        int tn = t + 8;
        if (tn < T_STEPS) buf[t & 7] = cur2[(size_t)tn * STRIDE + idx];
        float rst = (mem > 1.0f) ? 1.0f : 0.0f;
        mem = __fsub_rn(__fadd_rn(__fmul_rn(0.95f, mem), cur), rst);
        size_t off = (size_t)t * STRIDE + idx;
        spk2[off] = (mem > 1.0f) ? 1.0f : 0.0f;
        mem2[off] = mem;
    }
}

// ---------------------------------------------------------------------------
extern "C" void kernel_launch(void* const* d_in, const int* in_sizes, int n_in,
                              void* d_out, int out_size, void* d_ws, size_t ws_size,
                              hipStream_t stream) {
    const float* x  = (const float*)d_in[0];   // (100, 256, 784)
    const float* w1 = (const float*)d_in[1];   // (512, 784)
    const float* b1 = (const float*)d_in[2];   // (512,)
    const float* w2 = (const float*)d_in[3];   // (10, 512)
    const float* b2 = (const float*)d_in[4];   // (10,)

    float* out = (float*)d_out;
    // Output tuple order: (cur2, spk2, spk1, mem2, mem1), each stacked over T.
    float* cur2_out = out;                       // 256000
    float* spk2_out = out + 256000;              // 256000
    float* spk1_out = out + 512000;              // 13107200
    float* mem2_out = out + 13619200;            // 256000
    float* mem1_out = out + 13875200;            // 13107200

    const int M = T_STEPS * BATCH;               // 25600

    // P2 scratch: prefer d_ws (no aliasing); fall back to spk1 region
    // (per-thread-column safe aliasing) only if workspace is too small.
    const size_t p2_bytes = (size_t)M * NHID * sizeof(float);   // 52.4 MB
    float* p2buf = (d_ws != nullptr && ws_size >= p2_bytes)
                       ? (float*)d_ws : spk1_out;

    // 1) P1 -> mem1 region, P2 -> p2buf, one z=2 launch.
    dim3 gp(M / BM, NHID / BN, 2);               // (200, 4, 2) = 1600 blocks
    gemm1_dual<<<gp, 256, 0, stream>>>(x, w1, mem1_out, p2buf);

    // 2) hidden Leaky chains + P3 tail fold + bias (fp32 _rn):
    //    reads P1 (mem1 region) + P2 (p2buf), writes mem1 + spk1.
    leaky_hidden_fused<<<(BATCH * NHID) / 256, 256, 0, stream>>>(
        mem1_out, p2buf, spk1_out, x, w1, b1);

    // 3) cur2 = spk1 @ W2^T + b2 (f64 acc -> fp32)
    gemm2_f64<<<M / G2_ROWS, 320, 0, stream>>>(spk1_out, w2, b2, cur2_out);

    // 4) output Leaky chains (fp32 _rn): cur2 -> (spk2, mem2)
    leaky_out_kernel<<<(BATCH * NOUT + 255) / 256, 256, 0, stream>>>(
        cur2_out, spk2_out, mem2_out);
}

// Round 7
// 482.859 us; speedup vs baseline: 1.2779x; 1.0255x over previous
//
#include <hip/hip_runtime.h>
#include <stdint.h>

#define T_STEPS 100
#define BATCH   256
#define NIN     784
#define NHID    512
#define NOUT    10

// ===========================================================================
// NUMERICS CONTRACT (validated PASS R5/R6/R7/R12/R14 — do not break):
//   * gemm1: per C element, fp32 single-accumulator fmaf chain, k ascending,
//     OpenBLAS kc=384 panel folds: cur1 = ((P1 + P2) + P3) + bias, each +
//     a single __fadd_rn. Realized here as:
//       gemm1_dual z=0: C1 = acc(k 0..383)      (pure write, mem1 region)
//       gemm1_dual z=1: C2 = acc(k 384..767)    (pure write, d_ws scratch)
//       leaky_hidden_fused: cur = fadd(fadd(fadd(C1,C2),acc3),b1), where
//         acc3 = 16-k ascending fmaf chain (k 768..783) computed in-register.
//   * gemm2: f64 accumulation of fp32 products, +b2 in f64, single rounding.
//   * recurrences: fp32 _rn ops, ((0.95*mem + cur) - rst), no contraction;
//     spike/reset = (mem > 1.0f).
// PERF JOURNAL:
//   * R5 570us: 8x8 single-buf, VALUBusy 36%, latency-bound (2 waves/SIMD).
//   * R6 2144us: __launch_bounds__(256,3) clamped VGPR->84, scratch spill.
//   * R7 453us: dbuf 8x4, VGPR 148, VALUBusy 38% — LDS-pipe bound.
//   * R8 582us: 3-launch panel split -> 8x8 micro, BK=8, AGPR-clean acc
//     (VGPR 56), panels 2x155us.
//   * R9 645us REGRESSION: tail fused into GEMM epilogue -> VGPR 204.
//     LESSON: never touch acc non-trivially in the GEMM epilogue.
//   * R12 542.8us: z=2 dual-panel (265.7us, VGPR 56, occ 31%), P2 in d_ws,
//     tail+bias folded into leaky_hidden.
//   * R13 617us REGRESSION: BK=16 staging -> VGPR 176, occ 10%.
//     LESSON: BK=8 + one-float4-per-matrix staging keeps acc in AGPRs.
//   * R14 495.2us: gemm1 reverted (260.5us, VALUBusy 64%); leaky v2 (LDS
//     X-tail, acc3 pipelined, static ring) -42us.
//   * R15: remainder (234.7us vs ~75us BW floor) is latency-bound:
//     leaky_hidden ring 8->16 (prefetch lead 960->1920cy vs ~900cy HBM);
//     leaky_out loads all 100 cur2 into regs upfront (40 waves total, one
//     latency wait instead of 100). gemm1 untouched. NEXT: v_pk_fma_f32
//     packed-fp32 experiment on gemm1 (157TF issue ceiling vs 77TF now).
// ===========================================================================

// ---------------------------------------------------------------------------
// GEMM1 dual-panel kernel: z=0 -> k 0..383 into C1; z=1 -> k 384..767 into
// C2. BM=BN=128, BK=8, 256 threads = 4 waves in 2x2; each wave 8x8 lanes;
// micro 8x8. Double-buffered LDS, one barrier per iteration, prefetch-ahead.
// Pure overwrite, epilogue untouched (keeps acc in AGPRs, VGPR ~56).
// ---------------------------------------------------------------------------
#define BM 128
#define BN 128
#define BK 8
#define PANEL_K 384

__global__ __launch_bounds__(256) void gemm1_dual(
    const float* __restrict__ X, const float* __restrict__ W,
    float* __restrict__ C1, float* __restrict__ C2)
{
    __shared__ float As[2][BK][BM + 4];   // 2 x 4224 B
    __shared__ float Bs[2][BK][BN + 4];   // 2 x 4224 B

    const int tid = threadIdx.x;
    const int bm  = blockIdx.x * BM;
    const int bn  = blockIdx.y * BN;
    const int kb  = blockIdx.z ? PANEL_K : 0;
    float* __restrict__ C = blockIdx.z ? C2 : C1;

    // staging: 128 rows x 8 k = 256 float4
    const int row  = tid >> 1;           // 0..127
    const int koff = (tid & 1) * 4;      // 0 or 4

    // compute mapping: wave 2x2, lane 8x8, micro 8x8
    const int w    = tid >> 6;
    const int lane = tid & 63;
    const int tm   = (w & 1) * 64 + (lane & 7) * 8;    // 0..120
    const int tn   = (w >> 1) * 64 + (lane >> 3) * 8;  // 0..120

    float acc[8][8];
    #pragma unroll
    for (int i = 0; i < 8; ++i)
        #pragma unroll
        for (int j = 0; j < 8; ++j) acc[i][j] = 0.f;

    const float* Xp = X + (size_t)(bm + row) * NIN + kb + koff;
    const float* Wp = W + (size_t)(bn + row) * NIN + kb + koff;

    // prologue: stage iter 0 into buffer 0
    float4 pa = *(const float4*)(Xp);
    float4 pb = *(const float4*)(Wp);
    As[0][koff+0][row] = pa.x; As[0][koff+1][row] = pa.y;
    As[0][koff+2][row] = pa.z; As[0][koff+3][row] = pa.w;
    Bs[0][koff+0][row] = pb.x; Bs[0][koff+1][row] = pb.y;
    Bs[0][koff+2][row] = pb.z; Bs[0][koff+3][row] = pb.w;

    const int NITER = PANEL_K / BK;   // 48
    for (int it = 0; it < NITER; ++it) {
        const int cur = it & 1;
        __syncthreads();

        if (it + 1 < NITER) {
            const int k0 = (it + 1) * BK;
            pa = *(const float4*)(Xp + k0);
            pb = *(const float4*)(Wp + k0);
        }

        #pragma unroll
        for (int kk = 0; kk < BK; ++kk) {   // k ascending
            float4 av0 = *(const float4*)&As[cur][kk][tm];
            float4 av1 = *(const float4*)&As[cur][kk][tm + 4];
            float4 bv0 = *(const float4*)&Bs[cur][kk][tn];
            float4 bv1 = *(const float4*)&Bs[cur][kk][tn + 4];
            float a[8] = {av0.x, av0.y, av0.z, av0.w, av1.x, av1.y, av1.z, av1.w};
            float b[8] = {bv0.x, bv0.y, bv0.z, bv0.w, bv1.x, bv1.y, bv1.z, bv1.w};
            #pragma unroll
            for (int i = 0; i < 8; ++i)
                #pragma unroll
                for (int j = 0; j < 8; ++j)
                    acc[i][j] = fmaf(a[i], b[j], acc[i][j]);
        }

        if (it + 1 < NITER) {
            const int nxt = cur ^ 1;
            As[nxt][koff+0][row] = pa.x; As[nxt][koff+1][row] = pa.y;
            As[nxt][koff+2][row] = pa.z; As[nxt][koff+3][row] = pa.w;
            Bs[nxt][koff+0][row] = pb.x; Bs[nxt][koff+1][row] = pb.y;
            Bs[nxt][koff+2][row] = pb.z; Bs[nxt][koff+3][row] = pb.w;
        }
    }

    #pragma unroll
    for (int i = 0; i < 8; ++i) {
        size_t r = (size_t)(bm + tm + i) * NHID + bn + tn;
        *(float4*)&C[r]     = make_float4(acc[i][0], acc[i][1], acc[i][2], acc[i][3]);
        *(float4*)&C[r + 4] = make_float4(acc[i][4], acc[i][5], acc[i][6], acc[i][7]);
    }
}

// ---------------------------------------------------------------------------
// Hidden Leaky recurrence, fused with the GEMM1 tail fold (v3):
//   cur = fadd(fadd(fadd(P1, P2), acc3), b1)     [acc3 = 16-k fmaf chain]
//   mem = fsub(fadd(fmul(0.95, mem), cur), rst)
// One thread per (b,h) chain (131072) = 2 waves/SIMD (fixed TLP) -> must be
// ILP-deep: ring prefetch depth 16 (lead ~1920cy > ~900cy HBM miss). Block =
// 256 threads = one batch-row half; block's X-tail (6.4 KB) staged once in
// LDS (broadcast reads); acc3 computed one step ahead. t-loop statically
// unrolled so ring indices are compile-time. Bit-exact chain.
// ---------------------------------------------------------------------------
__global__ __launch_bounds__(256) void leaky_hidden_fused(
    float* __restrict__ mem_io,        // P1 on entry, mem1 on exit
    const float* __restrict__ c2,      // P2 partial (d_ws)
    float* __restrict__ spk_out,
    const float* __restrict__ X,
    const float* __restrict__ W1,
    const float* __restrict__ b1)
{
    __shared__ float4 xs4[T_STEPS][4];   // X[bb][t][768..783], 6.4 KB

    const int tid = threadIdx.x;
    const int idx = blockIdx.x * 256 + tid;    // 0..131071
    const size_t STRIDE = (size_t)BATCH * NHID;
    const int h  = idx & (NHID - 1);
    const int bb = idx >> 9;                   // uniform per block

    // stage X tail: 400 float4 across 256 threads
    {
        const float* xbase = X + (size_t)bb * NIN + 768;
        for (int e = tid; e < T_STEPS * 4; e += 256) {
            const int t = e >> 2, q = e & 3;
            xs4[t][q] = *(const float4*)(xbase + (size_t)t * BATCH * NIN + q * 4);
        }
    }

    // W1[h][768..783] -> 16 regs
    const float* wp = W1 + (size_t)h * NIN + 768;
    float4 w0 = *(const float4*)(wp);
    float4 w1v = *(const float4*)(wp + 4);
    float4 w2v = *(const float4*)(wp + 8);
    float4 w3v = *(const float4*)(wp + 12);
    const float wt[16] = {w0.x, w0.y, w0.z, w0.w, w1v.x, w1v.y, w1v.z, w1v.w,
                          w2v.x, w2v.y, w2v.z, w2v.w, w3v.x, w3v.y, w3v.z, w3v.w};
    const float bias = b1[h];

    float buf1[16], buf2[16];
    #pragma unroll
    for (int i = 0; i < 16; ++i) {
        buf1[i] = mem_io[idx + (size_t)i * STRIDE];
        buf2[i] = c2[idx + (size_t)i * STRIDE];
    }

    __syncthreads();   // xs4 ready

    // acc3 for t=0 (identical k-ascending chain, LDS-sourced)
    float a3cur;
    {
        float4 v0 = xs4[0][0], v1 = xs4[0][1], v2 = xs4[0][2], v3 = xs4[0][3];
        float a = 0.f;
        a = fmaf(v0.x, wt[0], a);  a = fmaf(v0.y, wt[1], a);
        a = fmaf(v0.z, wt[2], a);  a = fmaf(v0.w, wt[3], a);
        a = fmaf(v1.x, wt[4], a);  a = fmaf(v1.y, wt[5], a);
        a = fmaf(v1.z, wt[6], a);  a = fmaf(v1.w, wt[7], a);
        a = fmaf(v2.x, wt[8], a);  a = fmaf(v2.y, wt[9], a);
        a = fmaf(v2.z, wt[10], a); a = fmaf(v2.w, wt[11], a);
        a = fmaf(v3.x, wt[12], a); a = fmaf(v3.y, wt[13], a);
        a = fmaf(v3.z, wt[14], a); a = fmaf(v3.w, wt[15], a);
        a3cur = a;
    }

    float mem = 0.f;

    #define LH_BODY(T_, J_)                                                   \
    {                                                                         \
        const int t_ = (T_);                                                  \
        const float p1 = buf1[(J_)];                                          \
        const float p2 = buf2[(J_)];                                          \
        if (t_ + 16 < T_STEPS) {                                              \
            buf1[(J_)] = mem_io[idx + (size_t)(t_ + 16) * STRIDE];            \
            buf2[(J_)] = c2[idx + (size_t)(t_ + 16) * STRIDE];                \
        }                                                                     \
        float a3next = 0.f;                                                   \
        if (t_ + 1 < T_STEPS) {                                               \
            float4 v0 = xs4[t_ + 1][0], v1 = xs4[t_ + 1][1];                  \
            float4 v2 = xs4[t_ + 1][2], v3 = xs4[t_ + 1][3];                  \
            float a = 0.f;                                                    \
            a = fmaf(v0.x, wt[0], a);  a = fmaf(v0.y, wt[1], a);              \
            a = fmaf(v0.z, wt[2], a);  a = fmaf(v0.w, wt[3], a);              \
            a = fmaf(v1.x, wt[4], a);  a = fmaf(v1.y, wt[5], a);              \
            a = fmaf(v1.z, wt[6], a);  a = fmaf(v1.w, wt[7], a);              \
            a = fmaf(v2.x, wt[8], a);  a = fmaf(v2.y, wt[9], a);              \
            a = fmaf(v2.z, wt[10], a); a = fmaf(v2.w, wt[11], a);             \
            a = fmaf(v3.x, wt[12], a); a = fmaf(v3.y, wt[13], a);             \
            a3next = a;                                                       \
            a3next = fmaf(v3.z, wt[14], a3next);                              \
            a3next = fmaf(v3.w, wt[15], a3next);                              \
        }                                                                     \
        const float cur = __fadd_rn(__fadd_rn(__fadd_rn(p1, p2), a3cur), bias); \
        const float rst = (mem > 1.0f) ? 1.0f : 0.0f;                         \
        mem = __fsub_rn(__fadd_rn(__fmul_rn(0.95f, mem), cur), rst);          \
        const size_t off = idx + (size_t)t_ * STRIDE;                         \
        spk_out[off] = (mem > 1.0f) ? 1.0f : 0.0f;                            \
        mem_io[off]  = mem;                                                   \
        a3cur = a3next;                                                       \
    }

    for (int tb = 0; tb < 96; tb += 16) {   // tb = 0,16,32,48,64,80
        LH_BODY(tb + 0, 0)  LH_BODY(tb + 1, 1)  LH_BODY(tb + 2, 2)  LH_BODY(tb + 3, 3)
        LH_BODY(tb + 4, 4)  LH_BODY(tb + 5, 5)  LH_BODY(tb + 6, 6)  LH_BODY(tb + 7, 7)
        LH_BODY(tb + 8, 8)  LH_BODY(tb + 9, 9)  LH_BODY(tb + 10, 10) LH_BODY(tb + 11, 11)
        LH_BODY(tb + 12, 12) LH_BODY(tb + 13, 13) LH_BODY(tb + 14, 14) LH_BODY(tb + 15, 15)
    }
    // tail t = 96..99 (ring slots 0..3; no prefetch: t+16 >= 112 > 100)
    LH_BODY(96, 0) LH_BODY(97, 1) LH_BODY(98, 2) LH_BODY(99, 3)

    #undef LH_BODY
}

// ---------------------------------------------------------------------------
// GEMM2: cur2[m][o] = fl32( f64( sum_k spk1[m][k]*W2[o][k] + b2[o] ) )
// W2 (20 KB) staged in LDS. Block = 320 threads = 32 rows x 10 outputs.
// ---------------------------------------------------------------------------
#define G2_ROWS 32

__global__ __launch_bounds__(320) void gemm2_f64(
    const float* __restrict__ spk1, const float* __restrict__ W2,
    const float* __restrict__ b2, float* __restrict__ cur2)
{
    __shared__ float w2s[NOUT * NHID];  // 20 KB
    const int tid = threadIdx.x;
    for (int i = tid; i < NOUT * NHID; i += 320) w2s[i] = W2[i];
    __syncthreads();

    const int r = tid / NOUT;   // 0..31
    const int o = tid % NOUT;   // 0..9
    const size_t m = (size_t)blockIdx.x * G2_ROWS + r;
    const float* rowp = spk1 + m * NHID;
    const float* wp   = w2s + o * NHID;
    double dot = 0.0;
    #pragma unroll 4
    for (int k = 0; k < NHID; k += 4) {
        float4 s  = *(const float4*)(rowp + k);
        float4 wv = *(const float4*)(wp + k);
        dot = fma((double)s.x, (double)wv.x, dot);
        dot = fma((double)s.y, (double)wv.y, dot);
        dot = fma((double)s.z, (double)wv.z, dot);
        dot = fma((double)s.w, (double)wv.w, dot);
    }
    cur2[m * NOUT + o] = (float)(dot + (double)b2[o]);   // coalesced
}

// ---------------------------------------------------------------------------
// Output Leaky recurrence (fp32 _rn, v2): one thread per (b,o) chain (2560
// threads = 40 waves total -> occupancy irrelevant, latency is everything).
// Load ALL 100 cur2 values into registers upfront (independent loads, one
// latency wait), then run the serial recurrence from registers. Same op
// order per element -> bit-exact.
// ---------------------------------------------------------------------------
__global__ __launch_bounds__(256) void leaky_out_kernel(
    const float* __restrict__ cur2, float* __restrict__ spk2,
    float* __restrict__ mem2)
{
    const int idx = blockIdx.x * blockDim.x + threadIdx.x;
    if (idx >= BATCH * NOUT) return;
    const int STRIDE = BATCH * NOUT;

    float cur[T_STEPS];
    #pragma unroll
    for (int t = 0; t < T_STEPS; ++t)
        cur[t] = cur2[(size_t)t * STRIDE + idx];

    float mem = 0.f;
    #pragma unroll
    for (int t = 0; t < T_STEPS; ++t) {
        const float rst = (mem > 1.0f) ? 1.0f : 0.0f;
        mem = __fsub_rn(__fadd_rn(__fmul_rn(0.95f, mem), cur[t]), rst);
        const size_t off = (size_t)t * STRIDE + idx;
        spk2[off] = (mem > 1.0f) ? 1.0f : 0.0f;
        mem2[off] = mem;
    }
}

// ---------------------------------------------------------------------------
extern "C" void kernel_launch(void* const* d_in, const int* in_sizes, int n_in,
                              void* d_out, int out_size, void* d_ws, size_t ws_size,
                              hipStream_t stream) {
    const float* x  = (const float*)d_in[0];   // (100, 256, 784)
    const float* w1 = (const float*)d_in[1];   // (512, 784)
    const float* b1 = (const float*)d_in[2];   // (512,)
    const float* w2 = (const float*)d_in[3];   // (10, 512)
    const float* b2 = (const float*)d_in[4];   // (10,)

    float* out = (float*)d_out;
    // Output tuple order: (cur2, spk2, spk1, mem2, mem1), each stacked over T.
    float* cur2_out = out;                       // 256000
    float* spk2_out = out + 256000;              // 256000
    float* spk1_out = out + 512000;              // 13107200
    float* mem2_out = out + 13619200;            // 256000
    float* mem1_out = out + 13875200;            // 13107200

    const int M = T_STEPS * BATCH;               // 25600

    // P2 scratch: prefer d_ws (no aliasing); fall back to spk1 region
    // (per-thread-column safe aliasing) only if workspace is too small.
    const size_t p2_bytes = (size_t)M * NHID * sizeof(float);   // 52.4 MB
    float* p2buf = (d_ws != nullptr && ws_size >= p2_bytes)
                       ? (float*)d_ws : spk1_out;

    // 1) P1 -> mem1 region, P2 -> p2buf, one z=2 launch.
    dim3 gp(M / BM, NHID / BN, 2);               // (200, 4, 2) = 1600 blocks
    gemm1_dual<<<gp, 256, 0, stream>>>(x, w1, mem1_out, p2buf);

    // 2) hidden Leaky chains + P3 tail fold + bias (fp32 _rn):
    leaky_hidden_fused<<<(BATCH * NHID) / 256, 256, 0, stream>>>(
        mem1_out, p2buf, spk1_out, x, w1, b1);

    // 3) cur2 = spk1 @ W2^T + b2 (f64 acc -> fp32)
    gemm2_f64<<<M / G2_ROWS, 320, 0, stream>>>(spk1_out, w2, b2, cur2_out);

    // 4) output Leaky chains (fp32 _rn): cur2 -> (spk2, mem2)
    leaky_out_kernel<<<(BATCH * NOUT + 255) / 256, 256, 0, stream>>>(
        cur2_out, spk2_out, mem2_out);
}

// Round 8
// 468.906 us; speedup vs baseline: 1.3159x; 1.0298x over previous
//
#include <hip/hip_runtime.h>
#include <stdint.h>

#define T_STEPS 100
#define BATCH   256
#define NIN     784
#define NHID    512
#define NOUT    10

// ===========================================================================
// NUMERICS CONTRACT (validated PASS R5/R6/R7/R12/R14/R15 — do not break):
//   * gemm1: per C element, fp32 single-accumulator fmaf chain, k ascending,
//     OpenBLAS kc=384 panel folds: cur1 = ((P1 + P2) + P3) + bias, each +
//     a single __fadd_rn:
//       gemm1_dual z=0: C1 = acc(k 0..383)      (pure write, mem1 region)
//       gemm1_dual z=1: C2 = acc(k 384..767)    (pure write, d_ws scratch)
//       leaky_hidden_fused: cur = fadd(fadd(fadd(C1,C2),acc3),b1), where
//         acc3 = 16-k ascending fmaf chain (k 768..783) computed in-register.
//   * gemm2: f64 accumulation of fp32 products, +b2 in f64, single rounding.
//   * recurrences: fp32 _rn ops, ((0.95*mem + cur) - rst), no contraction;
//     spike/reset = (mem > 1.0f).
// PERF JOURNAL:
//   * R5 570us: 8x8 single-buf, latency-bound. R6 2144us: launch_bounds
//     min-waves clamp -> spill. R7 453us: LDS-pipe bound dbuf.
//   * R8 582us: panel split -> 8x8 micro BK=8, AGPR-clean acc (VGPR 56).
//   * R9 645us REGRESSION: tail in GEMM epilogue -> VGPR 204. LESSON:
//     never touch acc non-trivially in the GEMM epilogue.
//   * R12 542.8us: z=2 dual-panel (265.7us, VGPR 56, occ 31%), P2 in d_ws,
//     tail+bias folded into leaky_hidden.
//   * R13 617us REGRESSION: BK=16 staging -> VGPR 176. LESSON: BK=8 +
//     one-float4-per-matrix staging keeps acc in AGPRs.
//   * R14 495.2us: leaky v2 (LDS X-tail, acc3 pipelined, static ring).
//   * R15 482.9us: ring 16 + leaky_out reg-preload (-12us only -> the
//     1-thread-per-chain structure is latency-bound regardless of depth;
//     2 waves/SIMD can't both pipeline loads and run the serial chain).
//   * R16: leaky_hidden v4 = producer/consumer wave split. 512 thr/block:
//     tid<256 consumers (identical bit-exact chain math), tid>=256
//     producers stream P1/P2 -> LDS FIFO (2-buf x 8t x 256, 32KB) with 16
//     independent loads/chunk -> BW-bound. 13 barriers total. 512 blocks
//     all resident (4 waves/SIMD, 2x TLP). gemm1/gemm2/leaky_out untouched.
// ===========================================================================

// ---------------------------------------------------------------------------
// GEMM1 dual-panel kernel: z=0 -> k 0..383 into C1; z=1 -> k 384..767 into
// C2. BM=BN=128, BK=8, 256 threads = 4 waves in 2x2; each wave 8x8 lanes;
// micro 8x8. Double-buffered LDS, one barrier per iteration, prefetch-ahead.
// Pure overwrite, epilogue untouched (keeps acc in AGPRs, VGPR ~56).
// ---------------------------------------------------------------------------
#define BM 128
#define BN 128
#define BK 8
#define PANEL_K 384

__global__ __launch_bounds__(256) void gemm1_dual(
    const float* __restrict__ X, const float* __restrict__ W,
    float* __restrict__ C1, float* __restrict__ C2)
{
    __shared__ float As[2][BK][BM + 4];   // 2 x 4224 B
    __shared__ float Bs[2][BK][BN + 4];   // 2 x 4224 B

    const int tid = threadIdx.x;
    const int bm  = blockIdx.x * BM;
    const int bn  = blockIdx.y * BN;
    const int kb  = blockIdx.z ? PANEL_K : 0;
    float* __restrict__ C = blockIdx.z ? C2 : C1;

    // staging: 128 rows x 8 k = 256 float4
    const int row  = tid >> 1;           // 0..127
    const int koff = (tid & 1) * 4;      // 0 or 4

    // compute mapping: wave 2x2, lane 8x8, micro 8x8
    const int w    = tid >> 6;
    const int lane = tid & 63;
    const int tm   = (w & 1) * 64 + (lane & 7) * 8;    // 0..120
    const int tn   = (w >> 1) * 64 + (lane >> 3) * 8;  // 0..120

    float acc[8][8];
    #pragma unroll
    for (int i = 0; i < 8; ++i)
        #pragma unroll
        for (int j = 0; j < 8; ++j) acc[i][j] = 0.f;

    const float* Xp = X + (size_t)(bm + row) * NIN + kb + koff;
    const float* Wp = W + (size_t)(bn + row) * NIN + kb + koff;

    // prologue: stage iter 0 into buffer 0
    float4 pa = *(const float4*)(Xp);
    float4 pb = *(const float4*)(Wp);
    As[0][koff+0][row] = pa.x; As[0][koff+1][row] = pa.y;
    As[0][koff+2][row] = pa.z; As[0][koff+3][row] = pa.w;
    Bs[0][koff+0][row] = pb.x; Bs[0][koff+1][row] = pb.y;
    Bs[0][koff+2][row] = pb.z; Bs[0][koff+3][row] = pb.w;

    const int NITER = PANEL_K / BK;   // 48
    for (int it = 0; it < NITER; ++it) {
        const int cur = it & 1;
        __syncthreads();

        if (it + 1 < NITER) {
            const int k0 = (it + 1) * BK;
            pa = *(const float4*)(Xp + k0);
            pb = *(const float4*)(Wp + k0);
        }

        #pragma unroll
        for (int kk = 0; kk < BK; ++kk) {   // k ascending
            float4 av0 = *(const float4*)&As[cur][kk][tm];
            float4 av1 = *(const float4*)&As[cur][kk][tm + 4];
            float4 bv0 = *(const float4*)&Bs[cur][kk][tn];
            float4 bv1 = *(const float4*)&Bs[cur][kk][tn + 4];
            float a[8] = {av0.x, av0.y, av0.z, av0.w, av1.x, av1.y, av1.z, av1.w};
            float b[8] = {bv0.x, bv0.y, bv0.z, bv0.w, bv1.x, bv1.y, bv1.z, bv1.w};
            #pragma unroll
            for (int i = 0; i < 8; ++i)
                #pragma unroll
                for (int j = 0; j < 8; ++j)
                    acc[i][j] = fmaf(a[i], b[j], acc[i][j]);
        }

        if (it + 1 < NITER) {
            const int nxt = cur ^ 1;
            As[nxt][koff+0][row] = pa.x; As[nxt][koff+1][row] = pa.y;
            As[nxt][koff+2][row] = pa.z; As[nxt][koff+3][row] = pa.w;
            Bs[nxt][koff+0][row] = pb.x; Bs[nxt][koff+1][row] = pb.y;
            Bs[nxt][koff+2][row] = pb.z; Bs[nxt][koff+3][row] = pb.w;
        }
    }

    #pragma unroll
    for (int i = 0; i < 8; ++i) {
        size_t r = (size_t)(bm + tm + i) * NHID + bn + tn;
        *(float4*)&C[r]     = make_float4(acc[i][0], acc[i][1], acc[i][2], acc[i][3]);
        *(float4*)&C[r + 4] = make_float4(acc[i][4], acc[i][5], acc[i][6], acc[i][7]);
    }
}

// ---------------------------------------------------------------------------
// Hidden Leaky recurrence, fused with the GEMM1 tail fold (v4):
// producer/consumer wave specialization.
//   Block = 512 threads. tid<256: consumers, one (b,h) chain each, identical
//   bit-exact math:  cur = fadd(fadd(fadd(P1,P2),acc3),b1);
//                    mem = fsub(fadd(fmul(0.95,mem),cur),rst).
//   tid>=256: producers stream P1/P2 for the block's 256 chains into an LDS
//   double-buffered FIFO in chunks of 8 timesteps (16 independent global
//   loads per thread per chunk -> deep VMEM queue, BW-bound). One barrier
//   per chunk (13 total). LDS: 2 FIFOs 16KB each + X-tail 6.4KB = 38.4KB.
//   512 blocks x 8 waves all resident (2 blocks/CU, 4 waves/SIMD).
// Aliasing safety (ws-fallback where c2 == spk_out): producers read chunk
// c+1 while consumers write chunk c — t-ranges disjoint, barrier-ordered,
// and blocks own disjoint idx columns. Same for mem_io (P1 read ahead,
// mem written behind).
// ---------------------------------------------------------------------------
__global__ __launch_bounds__(512) void leaky_hidden_fused(
    float* __restrict__ mem_io,        // P1 on entry, mem1 on exit
    const float* c2,                   // P2 partial (d_ws; may alias spk_out)
    float* spk_out,
    const float* __restrict__ X,
    const float* __restrict__ W1,
    const float* __restrict__ b1)
{
    __shared__ float4 xs4[T_STEPS][4];    // X[bb][t][768..783], 6.4 KB
    __shared__ float  p1s[2][8][256];     // 8 KB x2
    __shared__ float  p2s[2][8][256];     // 8 KB x2

    const int tid  = threadIdx.x;
    const int lane256 = tid & 255;
    const int base = blockIdx.x * 256;              // chain base
    const size_t STRIDE = (size_t)BATCH * NHID;
    const int bb = base >> 9;                       // batch row (uniform)
    const size_t col = (size_t)base + lane256;      // this thread's chain/col

    // stage X tail (all 512 threads): 400 float4
    {
        const float* xbase = X + (size_t)bb * NIN + 768;
        for (int e = tid; e < T_STEPS * 4; e += 512) {
            const int t = e >> 2, q = e & 3;
            xs4[t][q] = *(const float4*)(xbase + (size_t)t * BATCH * NIN + q * 4);
        }
    }

    const bool producer = (tid >= 256);

    // consumer-only state (uniform dead regs for producers)
    float wt[16];
    float bias = 0.f;
    float mem  = 0.f;

    if (producer) {
        // prologue: chunk 0 (t = 0..7) into buf 0
        float v1[8], v2[8];
        #pragma unroll
        for (int j = 0; j < 8; ++j) {
            v1[j] = mem_io[col + (size_t)j * STRIDE];
            v2[j] = c2[col + (size_t)j * STRIDE];
        }
        #pragma unroll
        for (int j = 0; j < 8; ++j) {
            p1s[0][j][lane256] = v1[j];
            p2s[0][j][lane256] = v2[j];
        }
    } else {
        const int h = (int)(col & (NHID - 1));
        const float* wp = W1 + (size_t)h * NIN + 768;
        float4 w0  = *(const float4*)(wp);
        float4 w1v = *(const float4*)(wp + 4);
        float4 w2v = *(const float4*)(wp + 8);
        float4 w3v = *(const float4*)(wp + 12);
        wt[0]=w0.x;  wt[1]=w0.y;  wt[2]=w0.z;  wt[3]=w0.w;
        wt[4]=w1v.x; wt[5]=w1v.y; wt[6]=w1v.z; wt[7]=w1v.w;
        wt[8]=w2v.x; wt[9]=w2v.y; wt[10]=w2v.z; wt[11]=w2v.w;
        wt[12]=w3v.x; wt[13]=w3v.y; wt[14]=w3v.z; wt[15]=w3v.w;
        bias = b1[h];
    }

    __syncthreads();   // xs4 + chunk 0 ready

    // chunks: c = 0..12; chunk c covers t = 8c .. 8c+nt-1 (nt=4 for c=12)
    for (int c = 0; c <= 12; ++c) {
        if (producer) {
            if (c < 12) {
                const int t0 = (c + 1) * 8;
                const int nb = (c + 1 == 12) ? 4 : 8;
                float v1[8], v2[8];
                #pragma unroll
                for (int j = 0; j < 8; ++j) {
                    if (j < nb) {
                        v1[j] = mem_io[col + (size_t)(t0 + j) * STRIDE];
                        v2[j] = c2[col + (size_t)(t0 + j) * STRIDE];
                    }
                }
                const int pb = (c + 1) & 1;
                #pragma unroll
                for (int j = 0; j < 8; ++j) {
                    if (j < nb) {
                        p1s[pb][j][lane256] = v1[j];
                        p2s[pb][j][lane256] = v2[j];
                    }
                }
            }
        } else {
            const int nt = (c == 12) ? 4 : 8;
            const int cb = c & 1;
            #pragma unroll
            for (int j = 0; j < 8; ++j) {
                if (j < nt) {
                    const int t = c * 8 + j;
                    const float p1 = p1s[cb][j][lane256];
                    const float p2 = p2s[cb][j][lane256];
                    float4 v0 = xs4[t][0], v1 = xs4[t][1];
                    float4 v2 = xs4[t][2], v3 = xs4[t][3];
                    // acc3: 16-k ascending single-accumulator fmaf chain
                    float a = 0.f;
                    a = fmaf(v0.x, wt[0], a);  a = fmaf(v0.y, wt[1], a);
                    a = fmaf(v0.z, wt[2], a);  a = fmaf(v0.w, wt[3], a);
                    a = fmaf(v1.x, wt[4], a);  a = fmaf(v1.y, wt[5], a);
                    a = fmaf(v1.z, wt[6], a);  a = fmaf(v1.w, wt[7], a);
                    a = fmaf(v2.x, wt[8], a);  a = fmaf(v2.y, wt[9], a);
                    a = fmaf(v2.z, wt[10], a); a = fmaf(v2.w, wt[11], a);
                    a = fmaf(v3.x, wt[12], a); a = fmaf(v3.y, wt[13], a);
                    a = fmaf(v3.z, wt[14], a); a = fmaf(v3.w, wt[15], a);

                    const float cur = __fadd_rn(__fadd_rn(__fadd_rn(p1, p2), a), bias);
                    const float rst = (mem > 1.0f) ? 1.0f : 0.0f;
                    mem = __fsub_rn(__fadd_rn(__fmul_rn(0.95f, mem), cur), rst);

                    const size_t off = col + (size_t)t * STRIDE;
                    spk_out[off] = (mem > 1.0f) ? 1.0f : 0.0f;
                    mem_io[off]  = mem;
                }
            }
        }
        __syncthreads();
    }
}

// ---------------------------------------------------------------------------
// GEMM2: cur2[m][o] = fl32( f64( sum_k spk1[m][k]*W2[o][k] + b2[o] ) )
// W2 (20 KB) staged in LDS. Block = 320 threads = 32 rows x 10 outputs.
// ---------------------------------------------------------------------------
#define G2_ROWS 32

__global__ __launch_bounds__(320) void gemm2_f64(
    const float* __restrict__ spk1, const float* __restrict__ W2,
    const float* __restrict__ b2, float* __restrict__ cur2)
{
    __shared__ float w2s[NOUT * NHID];  // 20 KB
    const int tid = threadIdx.x;
    for (int i = tid; i < NOUT * NHID; i += 320) w2s[i] = W2[i];
    __syncthreads();

    const int r = tid / NOUT;   // 0..31
    const int o = tid % NOUT;   // 0..9
    const size_t m = (size_t)blockIdx.x * G2_ROWS + r;
    const float* rowp = spk1 + m * NHID;
    const float* wp   = w2s + o * NHID;
    double dot = 0.0;
    #pragma unroll 4
    for (int k = 0; k < NHID; k += 4) {
        float4 s  = *(const float4*)(rowp + k);
        float4 wv = *(const float4*)(wp + k);
        dot = fma((double)s.x, (double)wv.x, dot);
        dot = fma((double)s.y, (double)wv.y, dot);
        dot = fma((double)s.z, (double)wv.z, dot);
        dot = fma((double)s.w, (double)wv.w, dot);
    }
    cur2[m * NOUT + o] = (float)(dot + (double)b2[o]);   // coalesced
}

// ---------------------------------------------------------------------------
// Output Leaky recurrence (fp32 _rn, v2): one thread per (b,o) chain (2560
// threads = 40 waves -> occupancy irrelevant, latency is everything).
// Load ALL 100 cur2 values into registers upfront (independent loads, one
// latency wait), then run the serial recurrence from registers. Bit-exact.
// ---------------------------------------------------------------------------
__global__ __launch_bounds__(256) void leaky_out_kernel(
    const float* __restrict__ cur2, float* __restrict__ spk2,
    float* __restrict__ mem2)
{
    const int idx = blockIdx.x * blockDim.x + threadIdx.x;
    if (idx >= BATCH * NOUT) return;
    const int STRIDE = BATCH * NOUT;

    float cur[T_STEPS];
    #pragma unroll
    for (int t = 0; t < T_STEPS; ++t)
        cur[t] = cur2[(size_t)t * STRIDE + idx];

    float mem = 0.f;
    #pragma unroll
    for (int t = 0; t < T_STEPS; ++t) {
        const float rst = (mem > 1.0f) ? 1.0f : 0.0f;
        mem = __fsub_rn(__fadd_rn(__fmul_rn(0.95f, mem), cur[t]), rst);
        const size_t off = (size_t)t * STRIDE + idx;
        spk2[off] = (mem > 1.0f) ? 1.0f : 0.0f;
        mem2[off] = mem;
    }
}

// ---------------------------------------------------------------------------
extern "C" void kernel_launch(void* const* d_in, const int* in_sizes, int n_in,
                              void* d_out, int out_size, void* d_ws, size_t ws_size,
                              hipStream_t stream) {
    const float* x  = (const float*)d_in[0];   // (100, 256, 784)
    const float* w1 = (const float*)d_in[1];   // (512, 784)
    const float* b1 = (const float*)d_in[2];   // (512,)
    const float* w2 = (const float*)d_in[3];   // (10, 512)
    const float* b2 = (const float*)d_in[4];   // (10,)

    float* out = (float*)d_out;
    // Output tuple order: (cur2, spk2, spk1, mem2, mem1), each stacked over T.
    float* cur2_out = out;                       // 256000
    float* spk2_out = out + 256000;              // 256000
    float* spk1_out = out + 512000;              // 13107200
    float* mem2_out = out + 13619200;            // 256000
    float* mem1_out = out + 13875200;            // 13107200

    const int M = T_STEPS * BATCH;               // 25600

    // P2 scratch: prefer d_ws (no aliasing); fall back to spk1 region
    // (chunk-disjoint, barrier-ordered aliasing) only if ws too small.
    const size_t p2_bytes = (size_t)M * NHID * sizeof(float);   // 52.4 MB
    float* p2buf = (d_ws != nullptr && ws_size >= p2_bytes)
                       ? (float*)d_ws : spk1_out;

    // 1) P1 -> mem1 region, P2 -> p2buf, one z=2 launch.
    dim3 gp(M / BM, NHID / BN, 2);               // (200, 4, 2) = 1600 blocks
    gemm1_dual<<<gp, 256, 0, stream>>>(x, w1, mem1_out, p2buf);

    // 2) hidden Leaky chains + P3 tail fold + bias (fp32 _rn),
    //    producer/consumer split: 512 blocks x 512 threads.
    leaky_hidden_fused<<<(BATCH * NHID) / 256, 512, 0, stream>>>(
        mem1_out, p2buf, spk1_out, x, w1, b1);

    // 3) cur2 = spk1 @ W2^T + b2 (f64 acc -> fp32)
    gemm2_f64<<<M / G2_ROWS, 320, 0, stream>>>(spk1_out, w2, b2, cur2_out);

    // 4) output Leaky chains (fp32 _rn): cur2 -> (spk2, mem2)
    leaky_out_kernel<<<(BATCH * NOUT + 255) / 256, 256, 0, stream>>>(
        cur2_out, spk2_out, mem2_out);
}